// Round 7
// baseline (3450.792 us; speedup 1.0000x reference)
//
#include <hip/hip_runtime.h>
#include <math.h>

#define NN 16384
#define SS 2048
#define TT 16
#define CHUNK 2048      // OpenBLAS sgemv_t_4.c NBMAX — frozen, bit-exactness
#define NCHUNK 8        // NN / CHUNK
#define RPB 16          // rows per block (16 rows x 8 chunks x 2 lanes = 256 thr)

// np.tanh(f32) mimic: evaluate in f64, round once to f32 (~correctly rounded)
__device__ __forceinline__ float tanh_cr(float a) {
    return (float)tanh((double)a);
}

// Reference fold (R6, verified): lane j of 8 holds stripe j;
// fold8 = xor4, xor1, xor2  ->  ((a0+a4)+(a1+a5)) + ((a2+a6)+(a3+a7))

// inp[s,t] -> inpT[t,s], f32: tanh(where(u >= 0.01f, u, 0))
__global__ void prep_inp(const float* __restrict__ in, float* __restrict__ inpT) {
    int i = blockIdx.x * blockDim.x + threadIdx.x;
    if (i < SS * TT) {
        int s = i / TT, t = i % TT;
        float v = in[i];
        v = (v >= 0.01f) ? v : 0.0f;
        inpT[t * SS + s] = tanh_cr(v);
    }
}

__global__ void map_init(int* __restrict__ map) {
    int i = blockIdx.x * blockDim.x + threadIdx.x;
    if (i < NN) map[i] = -1;
}

__global__ void map_scatter(const int* __restrict__ idx, int* __restrict__ map) {
    int s = blockIdx.x * blockDim.x + threadIdx.x;
    if (s < SS) map[idx[s]] = s;
}

__device__ __forceinline__ float fold8(float a) {
    a += __shfl_xor(a, 4, 64);
    a += __shfl_xor(a, 1, 64);
    a += __shfl_xor(a, 2, 64);
    return a;
}

// t=0: x0 = W[:, idx] @ inp0 ; K=2048 = one NBMAX chunk, 8 lanes/row,
// lane j owns stripe k === j (mod 8), sequential fmaf chain. (Unchanged R6.)
__global__ __launch_bounds__(256) void step0(const float* __restrict__ W,
                                             const int* __restrict__ idx,
                                             const float* __restrict__ inp0,
                                             float* __restrict__ x_out,
                                             float* __restrict__ out) {
    int gid = blockIdx.x * blockDim.x + threadIdx.x;
    int row = gid >> 3;
    int j   = gid & 7;
    if (row >= NN) return;
    const float* __restrict__ wrow = W + (size_t)row * NN;
    float acc = 0.0f;
    #pragma unroll 16
    for (int k = j; k < SS; k += 8)
        acc = fmaf(wrow[idx[k]], inp0[k], acc);
    float y = fold8(acc);
    if (j == 0) {
        float v = (y >= 0.01f) ? y : 0.0f;
        v = tanh_cr(5.0f * v);
        x_out[row] = v;
        out[(size_t)row * TT + 0] = v;
    }
}

// t>=1: y = W @ x. Bit-identical arithmetic to R6, restructured for BW:
//  - 2 lanes per (row,chunk) unit; lane h owns stripes 4h..4h+3 and loads
//    float4 at k = c0 + 8i + 4h  (same sequential fmaf chain per stripe).
//  - all 8 NBMAX chunks computed in parallel; per-chunk sums combined in
//    chunk order by one thread per row (matches y += chunk_sum sequence).
__global__ __launch_bounds__(256) void step_t(const float* __restrict__ W,
                                              const float* __restrict__ x_in,
                                              const float* __restrict__ inp_t,
                                              const int* __restrict__ map,
                                              float* __restrict__ x_out,
                                              float* __restrict__ out, int t) {
    __shared__ float partial[RPB][NCHUNK];
    int tid = threadIdx.x;
    int u  = tid >> 1;              // unit 0..127: (row_local, chunk)
    int h  = tid & 1;               // half: stripes 4h..4h+3
    int rl = u >> 3;                // row_local 0..15
    int c  = u & 7;                 // chunk 0..7
    int row = blockIdx.x * RPB + rl;
    const float* __restrict__ wbase = W + (size_t)row * NN + c * CHUNK + 4 * h;
    const float* __restrict__ xbase = x_in + c * CHUNK + 4 * h;

    float a0 = 0.f, a1 = 0.f, a2 = 0.f, a3 = 0.f;
    #pragma unroll 8
    for (int i = 0; i < CHUNK / 8; ++i) {
        float4 w  = *reinterpret_cast<const float4*>(wbase + 8 * i);
        float4 xv = *reinterpret_cast<const float4*>(xbase + 8 * i);
        a0 = fmaf(w.x, xv.x, a0);   // stripe 4h+0 chain, sequential in i
        a1 = fmaf(w.y, xv.y, a1);   // stripe 4h+1
        a2 = fmaf(w.z, xv.z, a2);   // stripe 4h+2
        a3 = fmaf(w.w, xv.w, a3);   // stripe 4h+3
    }
    // t_s = a_s + a_{s+4}: own + partner (commutative -> bit-equal both lanes)
    float b0 = a0 + __shfl_xor(a0, 1, 64);
    float b1 = a1 + __shfl_xor(a1, 1, 64);
    float b2 = a2 + __shfl_xor(a2, 1, 64);
    float b3 = a3 + __shfl_xor(a3, 1, 64);
    float csum = (b0 + b1) + (b2 + b3);   // == fold8 lane-0 value
    if (h == 0) partial[rl][c] = csum;
    __syncthreads();

    if (tid < RPB) {
        int r2 = blockIdx.x * RPB + tid;
        float y = partial[tid][0];
        #pragma unroll
        for (int cc = 1; cc < NCHUNK; ++cc) y += partial[tid][cc];  // chunk order
        int m = map[r2];
        if (m >= 0) y += inp_t[m];
        float v = (y >= 0.01f) ? y : 0.0f;
        v = tanh_cr(5.0f * v);
        x_out[r2] = v;
        out[(size_t)r2 * TT + t] = v;
    }
}

extern "C" void kernel_launch(void* const* d_in, const int* in_sizes, int n_in,
                              void* d_out, int out_size, void* d_ws, size_t ws_size,
                              hipStream_t stream) {
    const float* W    = (const float*)d_in[0];
    const float* intt = (const float*)d_in[1];
    const int*   idx  = (const int*)d_in[2];
    float* out = (float*)d_out;

    char* ws = (char*)d_ws;
    float* inpT = (float*)ws;                                   // T*S f32 (128 KiB)
    size_t off = (size_t)TT * SS * 4;
    int*   map  = (int*)(ws + off);                             // N ints (64 KiB)
    off += (size_t)NN * 4;
    float* xa   = (float*)(ws + off);                           // N f32
    float* xb   = xa + NN;                                      // N f32

    prep_inp<<<(SS * TT + 255) / 256, 256, 0, stream>>>(intt, inpT);
    map_init<<<NN / 256, 256, 0, stream>>>(map);
    map_scatter<<<SS / 256, 256, 0, stream>>>(idx, map);

    step0<<<NN * 8 / 256, 256, 0, stream>>>(W, idx, inpT, xa, out);

    float* xi_ = xa;
    float* xo_ = xb;
    for (int t = 1; t < TT; ++t) {
        step_t<<<NN / RPB, 256, 0, stream>>>(W, xi_, inpT + (size_t)t * SS,
                                             map, xo_, out, t);
        float* tmp = xi_; xi_ = xo_; xo_ = tmp;
    }
}